// Round 15
// baseline (67.597 us; speedup 1.0000x reference)
//
#include <hip/hip_runtime.h>
#include <hip/hip_bf16.h>
#include <math.h>

#define NB 16384
#define ND 128
#define NH 512
#define NO 128
#define NE 8
#define EPSF 2.2204460492503131e-16f

using bf16x8 = __attribute__((ext_vector_type(8))) short;
using f32x16 = __attribute__((ext_vector_type(16))) float;
using uint2v = __attribute__((ext_vector_type(2))) unsigned;

// ---- workspace layout (bytes) ----
#define WS_BLKCNT 0u                       // int  [256][8]
#define WS_BLKIMP 8192u                    // float[256][8]
#define WS_TOKID  16384u                   // int  [NE][256*128] (tok | which<<30)
#define WS_TOKGG  1064960u                 // float2[NB]
#define WS_XBF    1196032u                 // ushort[NB][ND]
#define WS_W1F    5390336u                 // ushort frag-linear w1 (1MB)
#define WS_W2F    6438912u                 // ushort frag-linear w2 (1MB)
#define WS_YST4   7487488u                 // ushort[NB][2][4][NO] gate-prescaled bf16 (33.5MB)

__device__ __forceinline__ unsigned f2bf(float f){
  unsigned u = __float_as_uint(f);
  u += 0x7FFFu + ((u >> 16) & 1u);
  return u >> 16;
}
__device__ __forceinline__ unsigned cvtpk(float lo, float hi){
  unsigned r;
  asm("v_cvt_pk_bf16_f32 %0, %1, %2" : "=v"(r) : "v"(lo), "v"(hi));
  return r;
}

// ============ prep: gating (0-255) + w1 pack (256-511) + w2 pack (512-767) — R11 verbatim
__global__ __launch_bounds__(256) void prep_kernel(
    const float* __restrict__ x, const float* __restrict__ wg,
    const float* __restrict__ w1, const float* __restrict__ w2,
    unsigned short* __restrict__ xbf, unsigned short* __restrict__ w1f,
    unsigned short* __restrict__ w2f, int* __restrict__ blk_cnt,
    float* __restrict__ blk_imp, int* __restrict__ tok_ids, float2* __restrict__ tok_gg){
  int bx = blockIdx.x, tid = threadIdx.x;
  if (bx >= 512){
    int u = (bx - 512)*256 + tid;
    int o = u & 127, hb = (u>>7)&3, c = (u>>9)&15, e = u>>13;
    int h0 = c*32 + (hb>>1)*16 + (hb&1)*8;
    const float* src = w2 + (size_t)e*NH*NO + (size_t)h0*NO + o;
    unsigned q[4];
    #pragma unroll
    for (int p = 0; p < 4; ++p)
      q[p] = f2bf(src[(2*p)*NO]) | (f2bf(src[(2*p+1)*NO]) << 16);
    *(uint4*)(w2f + (size_t)u*8) = make_uint4(q[0], q[1], q[2], q[3]);
    return;
  }
  if (bx >= 256){
    int u = (bx - 256)*256 + tid;
    int h32 = u & 31, db = (u>>5)&15, c = (u>>9)&15, e = u>>13;
    int d0 = (db>>1)*16 + (db&1)*8;
    int hg = c*32 + h32;
    const float* src = w1 + (size_t)e*ND*NH + (size_t)d0*NH + hg;
    unsigned q[4];
    #pragma unroll
    for (int p = 0; p < 4; ++p)
      q[p] = f2bf(src[(2*p)*NH]) | (f2bf(src[(2*p+1)*NH]) << 16);
    *(uint4*)(w1f + (size_t)u*8) = make_uint4(q[0], q[1], q[2], q[3]);
    return;
  }
  __shared__ int   lcnt[NE];
  __shared__ float limp[NE];
  if (tid < NE){ lcnt[tid] = 0; limp[tid] = 0.f; }
  __syncthreads();
  int tok  = bx*64 + (tid >> 2);
  int part = tid & 3;
  const float4* xr4 = (const float4*)(x + (size_t)tok*ND);
  double acc[NE];
  #pragma unroll
  for (int e = 0; e < NE; ++e) acc[e] = 0.0;
  #pragma unroll
  for (int j = 0; j < 8; ++j){
    int f4 = part + j*4;
    float4 v = xr4[f4];
    uint2 p;
    p.x = f2bf(v.x) | (f2bf(v.y) << 16);
    p.y = f2bf(v.z) | (f2bf(v.w) << 16);
    *(uint2*)(xbf + (size_t)tok*ND + f4*4) = p;
    const float4* wr = (const float4*)(wg + f4*32);
    float vm[4] = {v.x, v.y, v.z, v.w};
    #pragma unroll
    for (int m = 0; m < 4; ++m){
      float4 wa = wr[2*m], wb = wr[2*m+1];
      double d = (double)vm[m];
      acc[0] += d*(double)wa.x; acc[1] += d*(double)wa.y;
      acc[2] += d*(double)wa.z; acc[3] += d*(double)wa.w;
      acc[4] += d*(double)wb.x; acc[5] += d*(double)wb.y;
      acc[6] += d*(double)wb.z; acc[7] += d*(double)wb.w;
    }
  }
  #pragma unroll
  for (int e = 0; e < NE; ++e){
    acc[e] += __shfl_xor(acc[e], 1);
    acc[e] += __shfl_xor(acc[e], 2);
  }
  if (part == 0){
    int i0 = 0;
    double l0 = acc[0];
    #pragma unroll
    for (int e = 1; e < NE; ++e) if (acc[e] > l0){ l0 = acc[e]; i0 = e; }
    int i1 = (i0 == 0) ? 1 : 0;
    double l1 = acc[i1];
    #pragma unroll
    for (int e = 0; e < NE; ++e) if (e != i0 && acc[e] > l1){ l1 = acc[e]; i1 = e; }
    float e1 = expf((float)(l1 - l0));
    float g0 = 1.0f/(1.0f + e1);
    float g1 = e1/(1.0f + e1);
    int s0 = atomicAdd(&lcnt[i0], 1);
    int s1 = atomicAdd(&lcnt[i1], 1);
    atomicAdd(&limp[i0], g0);
    atomicAdd(&limp[i1], g1);
    tok_gg[tok] = make_float2(g0, g1);
    tok_ids[i0*32768 + bx*128 + s0] = tok;
    tok_ids[i1*32768 + bx*128 + s1] = tok | (1 << 30);
  }
  __syncthreads();
  if (tid < NE){
    blk_cnt[bx*8 + tid] = lcnt[tid];
    blk_imp[bx*8 + tid] = limp[tid];
  }
}

// ============ experts: 2080 blocks = 520 token-tiles x 4 h-quarters; 256 thr, 4 waves/SIMD
// target (__launch_bounds__(256,4), VGPR<=128). Wave (t,oh): 32 tok x 128h-quarter x 64 o.
// Stage1 duplicated across oh-waves (no cross-wave coupling); weights L2-direct; barriers
// only in the 9.5KB-LDS prologue. Output: gate-prescaled bf16 quarter-slabs.
__global__ __launch_bounds__(256, 4) void expert_kernel(
    const unsigned short* __restrict__ xbf, const unsigned short* __restrict__ w1f,
    const unsigned short* __restrict__ w2f, const float* __restrict__ b1,
    const float* __restrict__ b2, const int* __restrict__ blk_cnt,
    const int* __restrict__ tok_ids, const float2* __restrict__ tok_gg,
    unsigned short* __restrict__ ystage){
  __shared__ int cnt_l[NE*256];      // 8KB
  __shared__ int gp[256];            // 1KB
  __shared__ int totl[NE];
  __shared__ int sl_tok[64];         // [t][l31]
  int tid = threadIdx.x;
  { // transpose count matrix into LDS
    int4 a = *(const int4*)(blk_cnt + tid*8);
    int4 c4 = *(const int4*)(blk_cnt + tid*8 + 4);
    cnt_l[0*256+tid]=a.x;  cnt_l[1*256+tid]=a.y;  cnt_l[2*256+tid]=a.z;  cnt_l[3*256+tid]=a.w;
    cnt_l[4*256+tid]=c4.x; cnt_l[5*256+tid]=c4.y; cnt_l[6*256+tid]=c4.z; cnt_l[7*256+tid]=c4.w;
  }
  __syncthreads();
  { // group-8 sums + 32-wide shuffle scan per expert
    int e8 = tid >> 5, g8 = tid & 31;
    int s8 = 0;
    #pragma unroll
    for (int i = 0; i < 8; ++i) s8 += cnt_l[e8*256 + g8*8 + i];
    int pre = s8;
    #pragma unroll
    for (int st = 1; st < 32; st <<= 1){
      int o = __shfl_up(pre, st, 32);
      if (g8 >= st) pre += o;
    }
    gp[tid] = pre;
    if (g8 == 31) totl[e8] = pre;
  }
  __syncthreads();
  int tb[9];
  tb[0] = 0;
  #pragma unroll
  for (int e2 = 0; e2 < NE; ++e2) tb[e2+1] = tb[e2] + ((totl[e2] + 63) >> 6);
  int tile_g = blockIdx.x >> 2, q = blockIdx.x & 3;
  if (tile_g >= tb[8]) return;
  int e = 0;
  #pragma unroll
  for (int ee = 1; ee < NE; ++ee) if (tb[ee] <= tile_g) e = ee;
  int n_e  = totl[e];
  int base = (tile_g - tb[e])*64;
  int lane = tid & 63, wid = tid >> 6, l31 = lane & 31, hi = lane >> 5;
  int t = wid & 1, oh = wid >> 1;
  // per-lane slot resolve (slot = base + t*32 + l31)
  int raw;
  {
    int s = base + t*32 + l31;
    if (s >= n_e) s = n_e - 1;
    int g = 0;
    #pragma unroll
    for (int st = 16; st; st >>= 1){
      int c = g + st;
      if (c <= 31 && gp[e*32 + c - 1] <= s) g = c;
    }
    int acc2 = g ? gp[e*32 + g - 1] : 0;
    int gb = g*8;
    while (true){
      int c2 = cnt_l[e*256 + gb];
      if (acc2 + c2 > s) break;
      acc2 += c2; ++gb;
    }
    raw = tok_ids[e*32768 + gb*128 + (s - acc2)];
  }
  if (oh == 0) sl_tok[t*32 + l31] = raw;
  __syncthreads();

  int tok0 = raw & 0x3FFFFFFF;
  bf16x8 xf[8];
  #pragma unroll
  for (int k = 0; k < 8; ++k)
    xf[k] = *(const bf16x8*)(xbf + (size_t)tok0*ND + (k*2 + hi)*8);
  const char* w1e = (const char*)w1f + (size_t)e*131072;
  const char* w2e = (const char*)w2f + (size_t)e*131072;

  f32x16 yacc[2];
  #pragma unroll
  for (int ot = 0; ot < 2; ++ot)
    #pragma unroll
    for (int i = 0; i < 16; ++i) yacc[ot][i] = 0.f;

  #pragma unroll
  for (int c = 0; c < 4; ++c){
    int c32 = q*4 + c;
    const char* w1c = w1e + (size_t)c32*8192;
    const char* w2c = w2e + (size_t)c32*8192;
    f32x16 hacc;
    #pragma unroll
    for (int i = 0; i < 16; ++i) hacc[i] = 0.f;
    #pragma unroll
    for (int k = 0; k < 8; ++k){
      bf16x8 a = *(const bf16x8*)(w1c + (k*2 + hi)*512 + l31*16);
      hacc = __builtin_amdgcn_mfma_f32_32x32x16_bf16(a, xf[k], hacc, 0, 0, 0);
    }
    const float4* b1p = (const float4*)(b1 + e*NH + c32*32 + hi*4);
    float dv[16];
    #pragma unroll
    for (int g = 0; g < 4; ++g){
      float4 bv = b1p[2*g];
      dv[4*g+0] = fmaxf(hacc[4*g+0] + bv.x, 0.f);
      dv[4*g+1] = fmaxf(hacc[4*g+1] + bv.y, 0.f);
      dv[4*g+2] = fmaxf(hacc[4*g+2] + bv.z, 0.f);
      dv[4*g+3] = fmaxf(hacc[4*g+3] + bv.w, 0.f);
    }
    unsigned A0 = cvtpk(dv[0], dv[1]),   A1 = cvtpk(dv[2], dv[3]);
    unsigned A2 = cvtpk(dv[4], dv[5]),   A3 = cvtpk(dv[6], dv[7]);
    unsigned A4 = cvtpk(dv[8], dv[9]),   A5 = cvtpk(dv[10], dv[11]);
    unsigned A6 = cvtpk(dv[12], dv[13]), A7 = cvtpk(dv[14], dv[15]);
    uint2v r0 = __builtin_amdgcn_permlane32_swap(A0, A2, false, false);
    uint2v r1 = __builtin_amdgcn_permlane32_swap(A1, A3, false, false);
    uint2v r2 = __builtin_amdgcn_permlane32_swap(A4, A6, false, false);
    uint2v r3 = __builtin_amdgcn_permlane32_swap(A5, A7, false, false);
    union { unsigned u[4]; bf16x8 v; } fa, fb;
    fa.u[0] = r0[0]; fa.u[1] = r1[0]; fa.u[2] = r0[1]; fa.u[3] = r1[1];
    fb.u[0] = r2[0]; fb.u[1] = r3[0]; fb.u[2] = r2[1]; fb.u[3] = r3[1];
    bf16x8 aht0 = fa.v, aht1 = fb.v;
    #pragma unroll
    for (int ot = 0; ot < 2; ++ot){
      int oidx = ((oh*2 + ot)*32 + l31)*16;
      bf16x8 bf0 = *(const bf16x8*)(w2c + hi*2048 + oidx);
      bf16x8 bf1 = *(const bf16x8*)(w2c + (2 + hi)*2048 + oidx);
      yacc[ot] = __builtin_amdgcn_mfma_f32_32x32x16_bf16(aht0, bf0, yacc[ot], 0, 0, 0);
      yacc[ot] = __builtin_amdgcn_mfma_f32_32x32x16_bf16(aht1, bf1, yacc[ot], 0, 0, 0);
    }
  }

  // epilogue: gate-prescaled bf16 into quarter-slab q (this wave's 32 tok x 64 o)
  float b2q = 0.25f;                        // b2 split evenly over 4 quarters
  float b2v[2];
  #pragma unroll
  for (int ot = 0; ot < 2; ++ot) b2v[ot] = b2[e*NO + (oh*2 + ot)*32 + l31]*b2q;
  #pragma unroll
  for (int r = 0; r < 16; ++r){
    int row = (r & 3) + 8*(r >> 2) + 4*hi;
    int slot = base + t*32 + row;
    if (slot < n_e){
      int rw = sl_tok[t*32 + row];
      int tk = rw & 0x3FFFFFFF, wh = (rw >> 30) & 1;
      float2 gg = tok_gg[tk];
      float gsc = wh ? gg.y : gg.x;
      unsigned short* dst = ystage + (((size_t)tk*2 + wh)*4 + q)*NO + l31;
      #pragma unroll
      for (int ot = 0; ot < 2; ++ot)
        dst[(oh*2 + ot)*32] = (unsigned short)f2bf((yacc[ot][r] + b2v[ot]) * gsc);
    }
  }
}

// ============ combine: y[tok] = sum of 8 slab rows (gate-prescaled bf16), eps-fix; loss in block 0
__global__ __launch_bounds__(256) void combine_kernel(
    const unsigned short* __restrict__ ystage, const int* __restrict__ blk_cnt,
    const float* __restrict__ blk_imp, float* __restrict__ y){
  if (blockIdx.x == 0){
    __shared__ int   scnt[32];
    __shared__ float simp[32];
    int tid = threadIdx.x, lane = tid & 63, wid = tid >> 6;
    int4 ca = *(const int4*)(blk_cnt + tid*8);
    int4 cb = *(const int4*)(blk_cnt + tid*8 + 4);
    float4 ia = *(const float4*)(blk_imp + tid*8);
    float4 ib = *(const float4*)(blk_imp + tid*8 + 4);
    int   cv[8] = {ca.x, ca.y, ca.z, ca.w, cb.x, cb.y, cb.z, cb.w};
    float iv[8] = {ia.x, ia.y, ia.z, ia.w, ib.x, ib.y, ib.z, ib.w};
    #pragma unroll
    for (int e = 0; e < NE; ++e){
      int   rc = cv[e];
      float ri = iv[e];
      #pragma unroll
      for (int st = 1; st < 64; st <<= 1){
        rc += __shfl_xor(rc, st);
        ri += __shfl_xor(ri, st);
      }
      if (lane == 0){ scnt[e*4 + wid] = rc; simp[e*4 + wid] = ri; }
    }
    __syncthreads();
    if (tid == 0){
      double si = 0, sqi = 0, sl = 0, sql = 0;
      #pragma unroll
      for (int e = 0; e < NE; ++e){
        double a = (double)(simp[e*4] + simp[e*4+1] + simp[e*4+2] + simp[e*4+3]);
        double bb = (double)(scnt[e*4] + scnt[e*4+1] + scnt[e*4+2] + scnt[e*4+3]);
        si += a; sqi += a*a; sl += bb; sql += bb*bb;
      }
      double mi = si/8.0, vi = (sqi - 8.0*mi*mi)/7.0;
      double ml = sl/8.0, vl = (sql - 8.0*ml*ml)/7.0;
      y[NB*NO] = (float)(vi/(mi*mi + 1e-10) + vl/(ml*ml + 1e-10));
    }
  }
  int idx = blockIdx.x*256 + threadIdx.x;    // 262144 threads, 8 outs each
  int tk = idx >> 4, oc = idx & 15;
  const unsigned short* rbase = ystage + (size_t)tk*8*NO + oc*8;
  float s[8] = {0.f,0.f,0.f,0.f,0.f,0.f,0.f,0.f};
  #pragma unroll
  for (int wq = 0; wq < 8; ++wq){
    uint4 a = *(const uint4*)(rbase + (size_t)wq*NO);
    unsigned aw[4] = {a.x, a.y, a.z, a.w};
    #pragma unroll
    for (int i = 0; i < 4; ++i){
      s[2*i]   += __uint_as_float(aw[i] << 16);
      s[2*i+1] += __uint_as_float(aw[i] & 0xFFFF0000u);
    }
  }
  #pragma unroll
  for (int i = 0; i < 8; ++i) s[i] = (s[i] == 0.f) ? EPSF : s[i];
  float4 o0 = {s[0], s[1], s[2], s[3]};
  float4 o1 = {s[4], s[5], s[6], s[7]};
  float* dst = y + (size_t)tk*128 + oc*8;
  *(float4*)dst     = o0;
  *(float4*)(dst+4) = o1;
}

extern "C" void kernel_launch(void* const* d_in, const int* in_sizes, int n_in,
                              void* d_out, int out_size, void* d_ws, size_t ws_size,
                              hipStream_t stream){
  (void)in_sizes; (void)n_in; (void)out_size; (void)ws_size;
  const float* x  = (const float*)d_in[0];
  const float* wg = (const float*)d_in[1];
  const float* w1 = (const float*)d_in[2];
  const float* b1 = (const float*)d_in[3];
  const float* w2 = (const float*)d_in[4];
  const float* b2 = (const float*)d_in[5];
  float* out = (float*)d_out;
  char* ws = (char*)d_ws;
  int*            blk_cnt = (int*)(ws + WS_BLKCNT);
  float*          blk_imp = (float*)(ws + WS_BLKIMP);
  int*            tok_ids = (int*)(ws + WS_TOKID);
  float2*         tok_gg  = (float2*)(ws + WS_TOKGG);
  unsigned short* xbf     = (unsigned short*)(ws + WS_XBF);
  unsigned short* w1f     = (unsigned short*)(ws + WS_W1F);
  unsigned short* w2f     = (unsigned short*)(ws + WS_W2F);
  unsigned short* ystage  = (unsigned short*)(ws + WS_YST4);

  prep_kernel<<<768, 256, 0, stream>>>(x, wg, w1, w2, xbf, w1f, w2f,
                                       blk_cnt, blk_imp, tok_ids, tok_gg);
  expert_kernel<<<2080, 256, 0, stream>>>(xbf, w1f, w2f, b1, b2,
                                          blk_cnt, tok_ids, tok_gg, ystage);
  combine_kernel<<<1024, 256, 0, stream>>>(ystage, blk_cnt, blk_imp, out);
}

// Round 16
// 47.651 us; speedup vs baseline: 1.4186x; 1.4186x over previous
//
#include <hip/hip_runtime.h>
#include <hip/hip_bf16.h>
#include <math.h>

#define NB 16384
#define ND 128
#define NH 512
#define NO 128
#define NE 8
#define EPSF 2.2204460492503131e-16f

using bf16x8 = __attribute__((ext_vector_type(8))) short;
using f32x16 = __attribute__((ext_vector_type(16))) float;
using uint2v = __attribute__((ext_vector_type(2))) unsigned;

// ---- workspace layout (bytes) ----
#define WS_BLKCNT 0u                       // int  [256][8]
#define WS_BLKIMP 8192u                    // float[256][8]
#define WS_TOKID  16384u                   // int  [NE][256*128] (tok | which<<30)
#define WS_TOKGG  1064960u                 // float2[NB]
#define WS_XBF    1196032u                 // ushort[NB][ND]
#define WS_W1F    5390336u                 // ushort frag-linear w1 (1MB)
#define WS_W2F    6438912u                 // ushort frag-linear w2 (1MB)
#define WS_YSTAGE 7487488u                 // ushort[NB][2][NO] gate-prescaled bf16 (8.4MB)

__device__ __forceinline__ unsigned f2bf(float f){
  unsigned u = __float_as_uint(f);
  u += 0x7FFFu + ((u >> 16) & 1u);
  return u >> 16;
}
__device__ __forceinline__ unsigned cvtpk(float lo, float hi){
  unsigned r;
  asm("v_cvt_pk_bf16_f32 %0, %1, %2" : "=v"(r) : "v"(lo), "v"(hi));
  return r;
}
__device__ __forceinline__ void gld16(const void* g, void* l){
  __builtin_amdgcn_global_load_lds((const __attribute__((address_space(1))) void*)g,
                                   (__attribute__((address_space(3))) void*)l, 16, 0, 0);
}

// ============ prep: gating (0-255) + w1 pack (256-511) + w2 pack (512-767) — R11 verbatim
__global__ __launch_bounds__(256) void prep_kernel(
    const float* __restrict__ x, const float* __restrict__ wg,
    const float* __restrict__ w1, const float* __restrict__ w2,
    unsigned short* __restrict__ xbf, unsigned short* __restrict__ w1f,
    unsigned short* __restrict__ w2f, int* __restrict__ blk_cnt,
    float* __restrict__ blk_imp, int* __restrict__ tok_ids, float2* __restrict__ tok_gg){
  int bx = blockIdx.x, tid = threadIdx.x;
  if (bx >= 512){
    int u = (bx - 512)*256 + tid;
    int o = u & 127, hb = (u>>7)&3, c = (u>>9)&15, e = u>>13;
    int h0 = c*32 + (hb>>1)*16 + (hb&1)*8;
    const float* src = w2 + (size_t)e*NH*NO + (size_t)h0*NO + o;
    unsigned q[4];
    #pragma unroll
    for (int p = 0; p < 4; ++p)
      q[p] = f2bf(src[(2*p)*NO]) | (f2bf(src[(2*p+1)*NO]) << 16);
    *(uint4*)(w2f + (size_t)u*8) = make_uint4(q[0], q[1], q[2], q[3]);
    return;
  }
  if (bx >= 256){
    int u = (bx - 256)*256 + tid;
    int h32 = u & 31, db = (u>>5)&15, c = (u>>9)&15, e = u>>13;
    int d0 = (db>>1)*16 + (db&1)*8;
    int hg = c*32 + h32;
    const float* src = w1 + (size_t)e*ND*NH + (size_t)d0*NH + hg;
    unsigned q[4];
    #pragma unroll
    for (int p = 0; p < 4; ++p)
      q[p] = f2bf(src[(2*p)*NH]) | (f2bf(src[(2*p+1)*NH]) << 16);
    *(uint4*)(w1f + (size_t)u*8) = make_uint4(q[0], q[1], q[2], q[3]);
    return;
  }
  __shared__ int   lcnt[NE];
  __shared__ float limp[NE];
  if (tid < NE){ lcnt[tid] = 0; limp[tid] = 0.f; }
  __syncthreads();
  int tok  = bx*64 + (tid >> 2);
  int part = tid & 3;
  const float4* xr4 = (const float4*)(x + (size_t)tok*ND);
  double acc[NE];
  #pragma unroll
  for (int e = 0; e < NE; ++e) acc[e] = 0.0;
  #pragma unroll
  for (int j = 0; j < 8; ++j){
    int f4 = part + j*4;
    float4 v = xr4[f4];
    uint2 p;
    p.x = f2bf(v.x) | (f2bf(v.y) << 16);
    p.y = f2bf(v.z) | (f2bf(v.w) << 16);
    *(uint2*)(xbf + (size_t)tok*ND + f4*4) = p;
    const float4* wr = (const float4*)(wg + f4*32);
    float vm[4] = {v.x, v.y, v.z, v.w};
    #pragma unroll
    for (int m = 0; m < 4; ++m){
      float4 wa = wr[2*m], wb = wr[2*m+1];
      double d = (double)vm[m];
      acc[0] += d*(double)wa.x; acc[1] += d*(double)wa.y;
      acc[2] += d*(double)wa.z; acc[3] += d*(double)wa.w;
      acc[4] += d*(double)wb.x; acc[5] += d*(double)wb.y;
      acc[6] += d*(double)wb.z; acc[7] += d*(double)wb.w;
    }
  }
  #pragma unroll
  for (int e = 0; e < NE; ++e){
    acc[e] += __shfl_xor(acc[e], 1);
    acc[e] += __shfl_xor(acc[e], 2);
  }
  if (part == 0){
    int i0 = 0;
    double l0 = acc[0];
    #pragma unroll
    for (int e = 1; e < NE; ++e) if (acc[e] > l0){ l0 = acc[e]; i0 = e; }
    int i1 = (i0 == 0) ? 1 : 0;
    double l1 = acc[i1];
    #pragma unroll
    for (int e = 0; e < NE; ++e) if (e != i0 && acc[e] > l1){ l1 = acc[e]; i1 = e; }
    float e1 = expf((float)(l1 - l0));
    float g0 = 1.0f/(1.0f + e1);
    float g1 = e1/(1.0f + e1);
    int s0 = atomicAdd(&lcnt[i0], 1);
    int s1 = atomicAdd(&lcnt[i1], 1);
    atomicAdd(&limp[i0], g0);
    atomicAdd(&limp[i1], g1);
    tok_gg[tok] = make_float2(g0, g1);
    tok_ids[i0*32768 + bx*128 + s0] = tok;
    tok_ids[i1*32768 + bx*128 + s1] = tok | (1 << 30);
  }
  __syncthreads();
  if (tid < NE){
    blk_cnt[bx*8 + tid] = lcnt[tid];
    blk_imp[bx*8 + tid] = limp[tid];
  }
}

// ============ experts: R11 core with T3/T4 counted-vmcnt pipeline.
// 128-tok tiles, 264 blocks, 4 waves. 8 PAIR iterations (2 chunks of 32h per pair,
// 64KB dbuf). Loop: STAGE(p+1) -> vmcnt(8) (pair p landed, p+1 in flight ACROSS the
// barrier) -> raw s_barrier -> compute -> lgkmcnt(0) -> raw s_barrier. No VMEM drain
// in the loop; b1 pre-staged to LDS so the loop has zero compiler-tracked VMEM.
__global__ __launch_bounds__(256) void expert_kernel(
    const unsigned short* __restrict__ xbf, const unsigned short* __restrict__ w1f,
    const unsigned short* __restrict__ w2f, const float* __restrict__ b1,
    const float* __restrict__ b2, const int* __restrict__ blk_cnt,
    const int* __restrict__ tok_ids, const float2* __restrict__ tok_gg,
    unsigned short* __restrict__ ystage){
  __shared__ char L[77440];
  char*  wbuf   = L;                      // [2][32768]: [slot]{w1 16K | w2 16K}
  int*   cnt_l  = (int*)(L + 65536);      // [8][256]
  int*   gp     = (int*)(L + 73728);      // [8][32]
  int*   sl_tok = (int*)(L + 74752);      // [128]
  float* b1s    = (float*)(L + 75264);    // [512]
  int*   totl   = (int*)(L + 77312);      // [8]
  int*   tbase  = (int*)(L + 77344);      // [9]
  int tid = threadIdx.x;
  { // load + transpose count matrix
    int4 a = *(const int4*)(blk_cnt + tid*8);
    int4 c4 = *(const int4*)(blk_cnt + tid*8 + 4);
    cnt_l[0*256+tid]=a.x;  cnt_l[1*256+tid]=a.y;  cnt_l[2*256+tid]=a.z;  cnt_l[3*256+tid]=a.w;
    cnt_l[4*256+tid]=c4.x; cnt_l[5*256+tid]=c4.y; cnt_l[6*256+tid]=c4.z; cnt_l[7*256+tid]=c4.w;
  }
  __syncthreads();
  { // group-8 sums + scan over 32 groups per expert
    int e8 = tid >> 5, g8 = tid & 31;
    int s8 = 0;
    #pragma unroll
    for (int i = 0; i < 8; ++i) s8 += cnt_l[e8*256 + g8*8 + i];
    int pre = s8;
    #pragma unroll
    for (int st = 1; st < 32; st <<= 1){
      int o = __shfl_up(pre, st, 32);
      if (g8 >= st) pre += o;
    }
    gp[tid] = pre;
    if (g8 == 31) totl[e8] = pre;
  }
  __syncthreads();
  if (tid == 0){
    tbase[0] = 0;
    #pragma unroll
    for (int e = 0; e < NE; ++e) tbase[e+1] = tbase[e] + ((totl[e] + 127) >> 7);
  }
  __syncthreads();
  int b = blockIdx.x;
  if (b >= tbase[8]) return;
  int e = 0;
  #pragma unroll
  for (int ee = 1; ee < NE; ++ee) if (tbase[ee] <= b) e = ee;
  int n_e  = totl[e];
  int base = (b - tbase[e])*128;
  if (tid < 128){                       // resolve 128 slots -> token ids
    int s = base + tid;
    if (s >= n_e) s = n_e - 1;
    int g = 0;
    #pragma unroll
    for (int st = 16; st; st >>= 1){
      int c = g + st;
      if (c <= 31 && gp[e*32 + c - 1] <= s) g = c;
    }
    int acc2 = g ? gp[e*32 + g - 1] : 0;
    int gb = g*8;
    while (true){
      int c2 = cnt_l[e*256 + gb];
      if (acc2 + c2 > s) break;
      acc2 += c2; ++gb;
    }
    sl_tok[tid] = tok_ids[e*32768 + gb*128 + (s - acc2)];
  }
  __syncthreads();

  int wid = tid >> 6, lane = tid & 63, l31 = lane & 31, hi = lane >> 5;
  const char* g1base = (const char*)w1f + (size_t)e*131072;
  const char* g2base = (const char*)w2f + (size_t)e*131072;

  int raw0 = sl_tok[wid*32 + l31];
  int tok0 = raw0 & 0x3FFFFFFF;
  bf16x8 xfrag[8];
  #pragma unroll
  for (int k = 0; k < 8; ++k)
    xfrag[k] = *(const bf16x8*)(xbf + (size_t)tok0*ND + (k*2 + hi)*8);
  // force xfrag completion so loop vmcnt counting is exact
  asm volatile("s_waitcnt vmcnt(0)" ::: "memory");
  __builtin_amdgcn_sched_barrier(0);
  // stage b1 (2KB) via gld16: waves 0-1 only (oldest VMEM op; drained by first vmcnt(8))
  if (wid < 2)
    gld16((const char*)(b1 + e*NH) + wid*1024 + lane*16, (char*)b1s + wid*1024);

  // pair p staging: 2 chunks = 32KB into slot (16K w1 + 16K w2)
#define STAGE(p, slot) do { \
    const char* _g1 = g1base + (size_t)(p)*16384 + wid*1024 + lane*16; \
    const char* _g2 = g2base + (size_t)(p)*16384 + wid*1024 + lane*16; \
    char* _l1 = wbuf + (slot)*32768 + wid*1024; \
    char* _l2 = wbuf + (slot)*32768 + 16384 + wid*1024; \
    _Pragma("unroll") \
    for (int _s = 0; _s < 4; ++_s){ \
      gld16(_g1 + _s*4096, _l1 + _s*4096); \
      gld16(_g2 + _s*4096, _l2 + _s*4096); \
    } \
  } while(0)

  STAGE(0, 0);
  f32x16 yacc[4];
  #pragma unroll
  for (int ot = 0; ot < 4; ++ot)
    #pragma unroll
    for (int i = 0; i < 16; ++i) yacc[ot][i] = 0.f;

  #pragma unroll
  for (int p = 0; p < 8; ++p){
    int slot = p & 1;
    if (p < 7) STAGE(p + 1, slot ^ 1);
    if (p < 7) asm volatile("s_waitcnt vmcnt(8)" ::: "memory");
    else       asm volatile("s_waitcnt vmcnt(0)" ::: "memory");
    __builtin_amdgcn_sched_barrier(0);
    __builtin_amdgcn_s_barrier();
    const char* w1p = wbuf + slot*32768;
    const char* w2p = wbuf + slot*32768 + 16384;
    #pragma unroll
    for (int sub = 0; sub < 2; ++sub){
      int c32 = p*2 + sub;
      f32x16 hacc;
      #pragma unroll
      for (int i = 0; i < 16; ++i) hacc[i] = 0.f;
      __builtin_amdgcn_s_setprio(1);
      #pragma unroll
      for (int k = 0; k < 8; ++k){
        bf16x8 a = *(const bf16x8*)(w1p + sub*8192 + (k*2 + hi)*512 + l31*16);
        hacc = __builtin_amdgcn_mfma_f32_32x32x16_bf16(a, xfrag[k], hacc, 0, 0, 0);
      }
      __builtin_amdgcn_s_setprio(0);
      float dv[16];
      #pragma unroll
      for (int g = 0; g < 4; ++g){
        float4 bv = *(const float4*)(b1s + c32*32 + hi*4 + g*8);
        dv[4*g+0] = fmaxf(hacc[4*g+0] + bv.x, 0.f);
        dv[4*g+1] = fmaxf(hacc[4*g+1] + bv.y, 0.f);
        dv[4*g+2] = fmaxf(hacc[4*g+2] + bv.z, 0.f);
        dv[4*g+3] = fmaxf(hacc[4*g+3] + bv.w, 0.f);
      }
      unsigned A0 = cvtpk(dv[0], dv[1]),   A1 = cvtpk(dv[2], dv[3]);
      unsigned A2 = cvtpk(dv[4], dv[5]),   A3 = cvtpk(dv[6], dv[7]);
      unsigned A4 = cvtpk(dv[8], dv[9]),   A5 = cvtpk(dv[10], dv[11]);
      unsigned A6 = cvtpk(dv[12], dv[13]), A7 = cvtpk(dv[14], dv[15]);
      uint2v r0 = __builtin_amdgcn_permlane32_swap(A0, A2, false, false);
      uint2v r1 = __builtin_amdgcn_permlane32_swap(A1, A3, false, false);
      uint2v r2 = __builtin_amdgcn_permlane32_swap(A4, A6, false, false);
      uint2v r3 = __builtin_amdgcn_permlane32_swap(A5, A7, false, false);
      union { unsigned u[4]; bf16x8 v; } fa, fb;
      fa.u[0] = r0[0]; fa.u[1] = r1[0]; fa.u[2] = r0[1]; fa.u[3] = r1[1];
      fb.u[0] = r2[0]; fb.u[1] = r3[0]; fb.u[2] = r2[1]; fb.u[3] = r3[1];
      bf16x8 aht0 = fa.v, aht1 = fb.v;
      __builtin_amdgcn_s_setprio(1);
      #pragma unroll
      for (int ot = 0; ot < 4; ++ot){
        bf16x8 bf0 = *(const bf16x8*)(w2p + sub*8192 + hi*2048 + (ot*32 + l31)*16);
        yacc[ot] = __builtin_amdgcn_mfma_f32_32x32x16_bf16(aht0, bf0, yacc[ot], 0, 0, 0);
        bf16x8 bf1 = *(const bf16x8*)(w2p + sub*8192 + (2 + hi)*2048 + (ot*32 + l31)*16);
        yacc[ot] = __builtin_amdgcn_mfma_f32_32x32x16_bf16(aht1, bf1, yacc[ot], 0, 0, 0);
      }
      __builtin_amdgcn_s_setprio(0);
    }
    asm volatile("s_waitcnt lgkmcnt(0)" ::: "memory");
    __builtin_amdgcn_sched_barrier(0);
    __builtin_amdgcn_s_barrier();
  }
#undef STAGE

  float b2v[4];
  #pragma unroll
  for (int ot = 0; ot < 4; ++ot) b2v[ot] = b2[e*NO + ot*32 + l31];
  #pragma unroll
  for (int r = 0; r < 16; ++r){
    int row = (r & 3) + 8*(r >> 2) + 4*hi;
    int slot = base + wid*32 + row;
    if (slot < n_e){
      int rw = sl_tok[wid*32 + row];
      int tk = rw & 0x3FFFFFFF, wh = (rw >> 30) & 1;
      float2 gg = tok_gg[tk];
      float g = wh ? gg.y : gg.x;
      unsigned short* dst = ystage + ((size_t)tk*2 + wh)*NO + l31;
      #pragma unroll
      for (int ot = 0; ot < 4; ++ot)
        dst[ot*32] = (unsigned short)f2bf((yacc[ot][r] + b2v[ot]) * g);
    }
  }
}

// ============ combine — R11 verbatim (y = row0+row1, eps-fix; loss in block 0)
__global__ __launch_bounds__(256) void combine_kernel(
    const unsigned short* __restrict__ ystage, const int* __restrict__ blk_cnt,
    const float* __restrict__ blk_imp, float* __restrict__ y){
  if (blockIdx.x == 0){
    __shared__ int   scnt[32];
    __shared__ float simp[32];
    int tid = threadIdx.x, lane = tid & 63, wid = tid >> 6;
    int4 ca = *(const int4*)(blk_cnt + tid*8);
    int4 cb = *(const int4*)(blk_cnt + tid*8 + 4);
    float4 ia = *(const float4*)(blk_imp + tid*8);
    float4 ib = *(const float4*)(blk_imp + tid*8 + 4);
    int   cv[8] = {ca.x, ca.y, ca.z, ca.w, cb.x, cb.y, cb.z, cb.w};
    float iv[8] = {ia.x, ia.y, ia.z, ia.w, ib.x, ib.y, ib.z, ib.w};
    #pragma unroll
    for (int e = 0; e < NE; ++e){
      int   rc = cv[e];
      float ri = iv[e];
      #pragma unroll
      for (int st = 1; st < 64; st <<= 1){
        rc += __shfl_xor(rc, st);
        ri += __shfl_xor(ri, st);
      }
      if (lane == 0){ scnt[e*4 + wid] = rc; simp[e*4 + wid] = ri; }
    }
    __syncthreads();
    if (tid == 0){
      double si = 0, sqi = 0, sl = 0, sql = 0;
      #pragma unroll
      for (int e = 0; e < NE; ++e){
        double a = (double)(simp[e*4] + simp[e*4+1] + simp[e*4+2] + simp[e*4+3]);
        double bb = (double)(scnt[e*4] + scnt[e*4+1] + scnt[e*4+2] + scnt[e*4+3]);
        si += a; sqi += a*a; sl += bb; sql += bb*bb;
      }
      double mi = si/8.0, vi = (sqi - 8.0*mi*mi)/7.0;
      double ml = sl/8.0, vl = (sql - 8.0*ml*ml)/7.0;
      y[NB*NO] = (float)(vi/(mi*mi + 1e-10) + vl/(ml*ml + 1e-10));
    }
  }
  int idx = blockIdx.x*256 + threadIdx.x;
  int tk = idx >> 4, q = idx & 15;
  const unsigned short* r0 = ystage + (size_t)tk*256 + q*8;
  uint4 a = *(const uint4*)r0;
  uint4 bq = *(const uint4*)(r0 + 128);
  unsigned aw[4] = {a.x, a.y, a.z, a.w};
  unsigned bw[4] = {bq.x, bq.y, bq.z, bq.w};
  float outs[8];
  #pragma unroll
  for (int i = 0; i < 4; ++i){
    float vlo = __uint_as_float(aw[i] << 16)         + __uint_as_float(bw[i] << 16);
    float vhi = __uint_as_float(aw[i] & 0xFFFF0000u) + __uint_as_float(bw[i] & 0xFFFF0000u);
    outs[2*i]   = (vlo == 0.f) ? EPSF : vlo;
    outs[2*i+1] = (vhi == 0.f) ? EPSF : vhi;
  }
  float4 o0 = {outs[0], outs[1], outs[2], outs[3]};
  float4 o1 = {outs[4], outs[5], outs[6], outs[7]};
  float* dst = y + (size_t)tk*128 + q*8;
  *(float4*)dst     = o0;
  *(float4*)(dst+4) = o1;
}

extern "C" void kernel_launch(void* const* d_in, const int* in_sizes, int n_in,
                              void* d_out, int out_size, void* d_ws, size_t ws_size,
                              hipStream_t stream){
  (void)in_sizes; (void)n_in; (void)out_size; (void)ws_size;
  const float* x  = (const float*)d_in[0];
  const float* wg = (const float*)d_in[1];
  const float* w1 = (const float*)d_in[2];
  const float* b1 = (const float*)d_in[3];
  const float* w2 = (const float*)d_in[4];
  const float* b2 = (const float*)d_in[5];
  float* out = (float*)d_out;
  char* ws = (char*)d_ws;
  int*            blk_cnt = (int*)(ws + WS_BLKCNT);
  float*          blk_imp = (float*)(ws + WS_BLKIMP);
  int*            tok_ids = (int*)(ws + WS_TOKID);
  float2*         tok_gg  = (float2*)(ws + WS_TOKGG);
  unsigned short* xbf     = (unsigned short*)(ws + WS_XBF);
  unsigned short* w1f     = (unsigned short*)(ws + WS_W1F);
  unsigned short* w2f     = (unsigned short*)(ws + WS_W2F);
  unsigned short* ystage  = (unsigned short*)(ws + WS_YSTAGE);

  prep_kernel<<<768, 256, 0, stream>>>(x, wg, w1, w2, xbf, w1f, w2f,
                                       blk_cnt, blk_imp, tok_ids, tok_gg);
  expert_kernel<<<264, 256, 0, stream>>>(xbf, w1f, w2f, b1, b2,
                                         blk_cnt, tok_ids, tok_gg, ystage);
  combine_kernel<<<1024, 256, 0, stream>>>(ystage, blk_cnt, blk_imp, out);
}